// Round 2
// baseline (216.120 us; speedup 1.0000x reference)
//
#include <hip/hip_runtime.h>

// Problem: N=4, L=S=4096, H=8, D=64, fp32 in/out.
// out[n,l,h,:] = (Qf[l]·KV) / (Qf[l]·Ksum + eps),  Qf=elu+1(Q), Kf=elu+1(K)
// KV[d][e] = sum_s Kf[s][d]*V[s][e];  Ksum[d] = sum_s Kf[s][d]
#define NB   4
#define LQ   4096
#define SK   4096
#define NHD  8
#define DD   64
#define ROWSTRIDE 512
#define NHTOT 32
#define EPSF 1e-6f

// k1 tiling
#define CH     32                 // S-chunks per (n,h) -> 1024 blocks
#define SROWS  (SK / CH)          // 128 s-rows per block
#define TS     32                 // staged rows per iteration
#define NITER  (SROWS / TS)       // 4
#define KVSZ   (DD * DD)          // 4096
#define PART_STRIDE (KVSZ + DD)   // 4160

// k1 shared-memory carve (floats)
#define KS_OFF   0                // 32*64
#define VS_OFF   2048             // 32*64
#define KRED_OFF 4096             // 16*64
#define BUF_PAD  66
#define BUFA_OFF 0                // 64*66 = 4224 (reuse after main loop)
#define BUFB_OFF 4224
#define SM_FLOATS 8448            // 33 KB -> 4 blocks/CU

__device__ __forceinline__ float fmap(float x) {
    return x > 0.f ? x + 1.f : __expf(x);   // elu(x)+1
}
__device__ __forceinline__ float4 fmap4(float4 v) {
    return make_float4(fmap(v.x), fmap(v.y), fmap(v.z), fmap(v.w));
}
__device__ __forceinline__ unsigned short f2bf(float f) {  // RNE bf16
    unsigned int u = __float_as_uint(f);
    return (unsigned short)((u + 0x7fffu + ((u >> 16) & 1u)) >> 16);
}

// ---------------------------------------------------------------------------
// k1: partial KV + Ksum per (nh, chunk). 256 thr = 4 waves; waves split the
// staged s-rows (8 each); 8x8 per-thread tile; cross-wave reduce in LDS.
// ---------------------------------------------------------------------------
__global__ __launch_bounds__(256, 4) void k1_kv(const float* __restrict__ Kin,
                                                const float* __restrict__ Vin,
                                                float* __restrict__ part) {
    __shared__ float sm[SM_FLOATS];
    const int blk   = blockIdx.x;
    const int nh    = blk >> 5;
    const int chunk = blk & 31;
    const int n = nh >> 3, h = nh & 7;
    const int t = threadIdx.x;
    const int w = t >> 6, lane = t & 63;
    const int d0 = (lane & 7) * 8;      // KV rows (d)
    const int e0 = (lane >> 3) * 8;     // KV cols (e)
    const int r = t >> 4;               // staging row 0..15 (and +16)
    const int c = (t & 15) * 4;         // staging col

    const size_t gbase = ((size_t)n * SK + (size_t)chunk * SROWS) * ROWSTRIDE
                         + (size_t)h * DD + c;
    const float* Kb = Kin + gbase;
    const float* Vb = Vin + gbase;

    float acc[8][8] = {};
    float ksl[4] = {0.f, 0.f, 0.f, 0.f};

    // prefetch tile 0
    float4 ka = *(const float4*)(Kb + (size_t)r * ROWSTRIDE);
    float4 kb = *(const float4*)(Kb + (size_t)(r + 16) * ROWSTRIDE);
    float4 va = *(const float4*)(Vb + (size_t)r * ROWSTRIDE);
    float4 vb = *(const float4*)(Vb + (size_t)(r + 16) * ROWSTRIDE);

    for (int it = 0; it < NITER; ++it) {
        float4 kfa = fmap4(ka), kfb = fmap4(kb);
        ksl[0] += kfa.x + kfb.x; ksl[1] += kfa.y + kfb.y;
        ksl[2] += kfa.z + kfb.z; ksl[3] += kfa.w + kfb.w;
        __syncthreads();                       // prev compute done reading LDS
        *(float4*)&sm[KS_OFF + r * DD + c]        = kfa;
        *(float4*)&sm[KS_OFF + (r + 16) * DD + c] = kfb;
        *(float4*)&sm[VS_OFF + r * DD + c]        = va;
        *(float4*)&sm[VS_OFF + (r + 16) * DD + c] = vb;
        __syncthreads();                       // stores visible
        if (it + 1 < NITER) {                  // prefetch next (overlaps compute)
            const size_t o = (size_t)(it + 1) * TS * ROWSTRIDE;
            ka = *(const float4*)(Kb + o + (size_t)r * ROWSTRIDE);
            kb = *(const float4*)(Kb + o + (size_t)(r + 16) * ROWSTRIDE);
            va = *(const float4*)(Vb + o + (size_t)r * ROWSTRIDE);
            vb = *(const float4*)(Vb + o + (size_t)(r + 16) * ROWSTRIDE);
        }
        const int sbase = w * 8;               // this wave's 8 s-rows
#pragma unroll
        for (int s = 0; s < 8; ++s) {
            const float* kr = &sm[KS_OFF + (sbase + s) * DD + d0];
            const float* vr = &sm[VS_OFF + (sbase + s) * DD + e0];
            float4 kA = *(const float4*)kr,       kB = *(const float4*)(kr + 4);
            float4 vA = *(const float4*)vr,       vB = *(const float4*)(vr + 4);
            float kk[8] = {kA.x, kA.y, kA.z, kA.w, kB.x, kB.y, kB.z, kB.w};
            float vv[8] = {vA.x, vA.y, vA.z, vA.w, vB.x, vB.y, vB.z, vB.w};
#pragma unroll
            for (int i = 0; i < 8; ++i)
#pragma unroll
                for (int j = 0; j < 8; ++j)
                    acc[i][j] += kk[i] * vv[j];
        }
    }

    // ---- Ksum reduce (ksred region doesn't overlap Ks/Vs; no barrier needed)
    *(float4*)&sm[KRED_OFF + r * DD + c] = make_float4(ksl[0], ksl[1], ksl[2], ksl[3]);
    __syncthreads();                                           // B1
    float ksumF = 0.f;
    if (w == 0) {
#pragma unroll
        for (int rr = 0; rr < 16; ++rr) ksumF += sm[KRED_OFF + rr * DD + lane];
    }
    __syncthreads();                                           // B2

    // ---- cross-wave KV reduce (float2, pad-66 rows)
    if (w == 2) {
#pragma unroll
        for (int i = 0; i < 8; ++i)
#pragma unroll
            for (int j = 0; j < 8; j += 2)
                *(float2*)&sm[BUFA_OFF + (d0 + i) * BUF_PAD + e0 + j] =
                    make_float2(acc[i][j], acc[i][j + 1]);
    }
    if (w == 3) {
#pragma unroll
        for (int i = 0; i < 8; ++i)
#pragma unroll
            for (int j = 0; j < 8; j += 2)
                *(float2*)&sm[BUFB_OFF + (d0 + i) * BUF_PAD + e0 + j] =
                    make_float2(acc[i][j], acc[i][j + 1]);
    }
    __syncthreads();                                           // B3
    if (w == 0) {
#pragma unroll
        for (int i = 0; i < 8; ++i)
#pragma unroll
            for (int j = 0; j < 8; j += 2) {
                float2 u = *(float2*)&sm[BUFA_OFF + (d0 + i) * BUF_PAD + e0 + j];
                acc[i][j] += u.x; acc[i][j + 1] += u.y;
            }
    }
    if (w == 1) {
#pragma unroll
        for (int i = 0; i < 8; ++i)
#pragma unroll
            for (int j = 0; j < 8; j += 2) {
                float2 u = *(float2*)&sm[BUFB_OFF + (d0 + i) * BUF_PAD + e0 + j];
                acc[i][j] += u.x; acc[i][j + 1] += u.y;
            }
    }
    __syncthreads();                                           // B4
    if (w == 1) {
#pragma unroll
        for (int i = 0; i < 8; ++i)
#pragma unroll
            for (int j = 0; j < 8; j += 2)
                *(float2*)&sm[BUFA_OFF + (d0 + i) * BUF_PAD + e0 + j] =
                    make_float2(acc[i][j], acc[i][j + 1]);
    }
    __syncthreads();                                           // B5
    if (w == 0) {
#pragma unroll
        for (int i = 0; i < 8; ++i)
#pragma unroll
            for (int j = 0; j < 8; j += 2) {
                float2 u = *(float2*)&sm[BUFA_OFF + (d0 + i) * BUF_PAD + e0 + j];
                acc[i][j] += u.x; acc[i][j + 1] += u.y;
            }
        float* pb = part + ((size_t)nh * CH + chunk) * PART_STRIDE;
#pragma unroll
        for (int i = 0; i < 8; ++i) {
            *(float4*)(pb + (d0 + i) * DD + e0) =
                make_float4(acc[i][0], acc[i][1], acc[i][2], acc[i][3]);
            *(float4*)(pb + (d0 + i) * DD + e0 + 4) =
                make_float4(acc[i][4], acc[i][5], acc[i][6], acc[i][7]);
        }
        pb[KVSZ + lane] = ksumF;
    }
}

// ---------------------------------------------------------------------------
// k2: sum CH partials -> final [nh][4160]
// ---------------------------------------------------------------------------
__global__ __launch_bounds__(256) void k2_reduce(const float* __restrict__ part,
                                                 float* __restrict__ fin) {
    const int idx = blockIdx.x * 256 + threadIdx.x;
    if (idx >= NHTOT * PART_STRIDE) return;
    const int nh = idx / PART_STRIDE;
    const int j  = idx - nh * PART_STRIDE;
    const float* p = part + (size_t)nh * CH * PART_STRIDE + j;
    float s = 0.f;
#pragma unroll
    for (int cx = 0; cx < CH; ++cx) s += p[(size_t)cx * PART_STRIDE];
    fin[idx] = s;
}

// ---------------------------------------------------------------------------
// k3: out = (Qf·KV) / (Qf·Ksum + eps). 128 thr (2 waves), LT=128 l-rows,
// 8x8 per-thread tile, Q staged in LDS as bf16 (halves LDS + fits 4 blk/CU).
// ---------------------------------------------------------------------------
#define LT3  128
#define QSTR 72   // ushort row stride: 16B-aligned, conflict-free reads
__global__ __launch_bounds__(128, 2) void k3_out(const float* __restrict__ Qin,
                                                 const float* __restrict__ fin,
                                                 float* __restrict__ out) {
    __shared__ unsigned short Qs[LT3 * QSTR];   // 18 KB
    __shared__ float KVs[DD * DD];              // 16 KB
    __shared__ float Ksm[DD];
    const int blk = blockIdx.x;
    const int nh  = blk >> 5;
    const int lc  = blk & 31;
    const int n = nh >> 3, h = nh & 7;
    const int t = threadIdx.x;
    const int w = t >> 6, lane = t & 63;

    // load final KV + Ksum
    const float* fb = fin + (size_t)nh * PART_STRIDE;
    for (int i = t * 4; i < KVSZ; i += 512)
        *(float4*)&KVs[i] = *(const float4*)(fb + i);
    if (t < DD) Ksm[t] = fb[KVSZ + t];

    // stage Q (feature-mapped, bf16)
    const int r = t >> 4, c = (t & 15) * 4;
    const float* Qb = Qin + ((size_t)n * LQ + (size_t)lc * LT3) * ROWSTRIDE
                      + (size_t)h * DD + c;
    for (int rr = r; rr < LT3; rr += 8) {
        float4 q = *(const float4*)(Qb + (size_t)rr * ROWSTRIDE);
        float4 qf = fmap4(q);
        unsigned int w0 = (unsigned int)f2bf(qf.x) | ((unsigned int)f2bf(qf.y) << 16);
        unsigned int w1 = (unsigned int)f2bf(qf.z) | ((unsigned int)f2bf(qf.w) << 16);
        *(uint2*)&Qs[rr * QSTR + c] = make_uint2(w0, w1);
    }
    __syncthreads();

    const int e0 = (lane >> 3) * 8;
    const int rbase = w * 64 + (lane & 7);     // rows rbase + 8i
    float acc[8][8] = {};
    float z[8] = {};

#pragma unroll
    for (int dch = 0; dch < DD; dch += 4) {
        float4 km4 = *(const float4*)&Ksm[dch];
        float kmv[4] = {km4.x, km4.y, km4.z, km4.w};
        float qf[8][4];
#pragma unroll
        for (int i = 0; i < 8; ++i) {
            uint2 qw = *(const uint2*)&Qs[(rbase + 8 * i) * QSTR + dch];
            qf[i][0] = __uint_as_float(qw.x << 16);
            qf[i][1] = __uint_as_float(qw.x & 0xffff0000u);
            qf[i][2] = __uint_as_float(qw.y << 16);
            qf[i][3] = __uint_as_float(qw.y & 0xffff0000u);
        }
        float kv[4][8];
#pragma unroll
        for (int dd = 0; dd < 4; ++dd) {
            float4 a = *(const float4*)&KVs[(dch + dd) * DD + e0];
            float4 b = *(const float4*)&KVs[(dch + dd) * DD + e0 + 4];
            kv[dd][0] = a.x; kv[dd][1] = a.y; kv[dd][2] = a.z; kv[dd][3] = a.w;
            kv[dd][4] = b.x; kv[dd][5] = b.y; kv[dd][6] = b.z; kv[dd][7] = b.w;
        }
#pragma unroll
        for (int i = 0; i < 8; ++i)
#pragma unroll
            for (int dd = 0; dd < 4; ++dd) {
                z[i] += qf[i][dd] * kmv[dd];
#pragma unroll
                for (int j = 0; j < 8; ++j)
                    acc[i][j] += qf[i][dd] * kv[dd][j];
            }
    }

    float* ob = out + ((size_t)n * LQ + (size_t)lc * LT3) * ROWSTRIDE
                + (size_t)h * DD;
#pragma unroll
    for (int i = 0; i < 8; ++i) {
        float zi = 1.f / (z[i] + EPSF);
        const size_t row = (size_t)(rbase + 8 * i) * ROWSTRIDE;
        *(float4*)(ob + row + e0) =
            make_float4(acc[i][0] * zi, acc[i][1] * zi, acc[i][2] * zi, acc[i][3] * zi);
        *(float4*)(ob + row + e0 + 4) =
            make_float4(acc[i][4] * zi, acc[i][5] * zi, acc[i][6] * zi, acc[i][7] * zi);
    }
}

// ---------------------------------------------------------------------------
extern "C" void kernel_launch(void* const* d_in, const int* in_sizes, int n_in,
                              void* d_out, int out_size, void* d_ws, size_t ws_size,
                              hipStream_t stream) {
    const float* Q = (const float*)d_in[0];
    const float* K = (const float*)d_in[1];
    const float* V = (const float*)d_in[2];
    float* out = (float*)d_out;

    float* ws   = (float*)d_ws;
    float* part = ws;                                        // 32*32*4160 floats (~17 MB)
    float* fin  = ws + (size_t)NHTOT * CH * PART_STRIDE;     // 32*4160 floats

    k1_kv<<<NHTOT * CH, 256, 0, stream>>>(K, V, part);
    k2_reduce<<<(NHTOT * PART_STRIDE + 255) / 256, 256, 0, stream>>>(part, fin);
    k3_out<<<NHTOT * (LQ / LT3), 128, 0, stream>>>(Q, fin, out);
}

// Round 3
// 165.436 us; speedup vs baseline: 1.3064x; 1.3064x over previous
//
#include <hip/hip_runtime.h>

// Problem: N=4, L=S=4096, H=8, D=64, fp32 in/out.
// out[n,l,h,:] = (Qf[l]·KV) / (Qf[l]·Ksum + eps),  Qf=elu+1(Q), Kf=elu+1(K)
// KV[d][e] = sum_s Kf[s][d]*V[s][e];  Ksum[d] = sum_s Kf[s][d]
#define NB   4
#define LQ   4096
#define SK   4096
#define NHD  8
#define DD   64
#define ROWSTRIDE 512
#define NHTOT 32
#define EPSF 1e-6f

// k1 tiling
#define CH     32                 // S-chunks per (n,h) -> 1024 blocks
#define SROWS  (SK / CH)          // 128 s-rows per block
#define TS     32                 // staged rows per iteration
#define NITER  (SROWS / TS)       // 4
#define KVSZ   (DD * DD)          // 4096
#define PART_STRIDE (KVSZ + DD)   // 4160

// k1 LDS carve (floats). Staging (stride 68) overlaid by reduce buffers.
#define SPAD     68
#define KS_OFF   0                // 32*68 = 2176
#define VS_OFF   2176             // 32*68 -> staging ends 4352
#define BUFA_OFF 0                // 64*64 = 4096 (after main loop)
#define BUFB_OFF 4096             // 64*64 -> 8192
#define KRED_OFF 8192             // 16*64 = 1024 (disjoint from staging+bufs)
#define SM_FLOATS 9216            // 36 KB -> 4 blocks/CU by LDS

__device__ __forceinline__ float fmap(float x) {
    return x > 0.f ? x + 1.f : __expf(x);   // elu(x)+1
}
__device__ __forceinline__ float4 fmap4(float4 v) {
    return make_float4(fmap(v.x), fmap(v.y), fmap(v.z), fmap(v.w));
}
__device__ __forceinline__ unsigned short f2bf(float f) {  // RNE bf16
    unsigned int u = __float_as_uint(f);
    return (unsigned short)((u + 0x7fffu + ((u >> 16) & 1u)) >> 16);
}

// ---------------------------------------------------------------------------
// k1: partial KV + Ksum per (nh, chunk). 256 thr = 4 waves split staged rows;
// 8x8 per-thread tile. part layout per block: flat lane-major chunks:
//   part[blk][c*256 + lane*4 + m] = acc[(4c+m)>>3][(4c+m)&7] of `lane`
//   part[blk][4096 + d]           = Ksum[d]
// VGPR: acc 64 + prefetch 16 + temps ~30 => ~120; (256,2) forbids the
// round-2 catastrophe (64-VGPR cap -> 137 MB scratch spill).
// ---------------------------------------------------------------------------
__global__ __launch_bounds__(256, 2) void k1_kv(const float* __restrict__ Kin,
                                                const float* __restrict__ Vin,
                                                float* __restrict__ part) {
    __shared__ float sm[SM_FLOATS];
    const int blk   = blockIdx.x;
    const int nh    = blk >> 5;
    const int chunk = blk & 31;
    const int n = nh >> 3, h = nh & 7;
    const int t = threadIdx.x;
    const int w = t >> 6, lane = t & 63;
    const int d0 = (lane & 7) * 8;      // KV rows (d)
    const int e0 = (lane >> 3) * 8;     // KV cols (e)
    const int r = t >> 4;               // staging row 0..15 (and +16)
    const int c = (t & 15) * 4;         // staging col

    const size_t gbase = ((size_t)n * SK + (size_t)chunk * SROWS) * ROWSTRIDE
                         + (size_t)h * DD + c;
    const float* Kb = Kin + gbase;
    const float* Vb = Vin + gbase;

    float acc[8][8] = {};
    float ksl[4] = {0.f, 0.f, 0.f, 0.f};

    // prefetch tile 0
    float4 ka = *(const float4*)(Kb + (size_t)r * ROWSTRIDE);
    float4 kb = *(const float4*)(Kb + (size_t)(r + 16) * ROWSTRIDE);
    float4 va = *(const float4*)(Vb + (size_t)r * ROWSTRIDE);
    float4 vb = *(const float4*)(Vb + (size_t)(r + 16) * ROWSTRIDE);

    for (int it = 0; it < NITER; ++it) {
        float4 kfa = fmap4(ka), kfb = fmap4(kb);
        ksl[0] += kfa.x + kfb.x; ksl[1] += kfa.y + kfb.y;
        ksl[2] += kfa.z + kfb.z; ksl[3] += kfa.w + kfb.w;
        __syncthreads();                       // prev compute done reading LDS
        *(float4*)&sm[KS_OFF + r * SPAD + c]        = kfa;
        *(float4*)&sm[KS_OFF + (r + 16) * SPAD + c] = kfb;
        *(float4*)&sm[VS_OFF + r * SPAD + c]        = va;
        *(float4*)&sm[VS_OFF + (r + 16) * SPAD + c] = vb;
        __syncthreads();                       // stores visible
        if (it + 1 < NITER) {                  // prefetch next (hidden by compute)
            const size_t o = (size_t)(it + 1) * TS * ROWSTRIDE;
            ka = *(const float4*)(Kb + o + (size_t)r * ROWSTRIDE);
            kb = *(const float4*)(Kb + o + (size_t)(r + 16) * ROWSTRIDE);
            va = *(const float4*)(Vb + o + (size_t)r * ROWSTRIDE);
            vb = *(const float4*)(Vb + o + (size_t)(r + 16) * ROWSTRIDE);
        }
        const int sbase = w * 8;               // this wave's 8 s-rows
#pragma unroll
        for (int s = 0; s < 8; ++s) {
            const float* kr = &sm[KS_OFF + (sbase + s) * SPAD + d0];
            const float* vr = &sm[VS_OFF + (sbase + s) * SPAD + e0];
            float4 kA = *(const float4*)kr, kB = *(const float4*)(kr + 4);
            float4 vA = *(const float4*)vr, vB = *(const float4*)(vr + 4);
            float kk[8] = {kA.x, kA.y, kA.z, kA.w, kB.x, kB.y, kB.z, kB.w};
            float vv[8] = {vA.x, vA.y, vA.z, vA.w, vB.x, vB.y, vB.z, vB.w};
#pragma unroll
            for (int i = 0; i < 8; ++i)
#pragma unroll
                for (int j = 0; j < 8; ++j)
                    acc[i][j] += kk[i] * vv[j];
        }
    }

    // Ksum partials -> KRED (disjoint region; no barrier needed before write)
    *(float4*)&sm[KRED_OFF + r * DD + c] = make_float4(ksl[0], ksl[1], ksl[2], ksl[3]);
    __syncthreads();                                           // B1
    float ksumF = 0.f;
    if (w == 0) {
#pragma unroll
        for (int rr = 0; rr < 16; ++rr) ksumF += sm[KRED_OFF + rr * DD + lane];
    }
    // cross-wave KV reduce. Lane-major float4 chunks, XOR-rotated slot:
    // chunk c of lane -> sm[BUF + lane*64 + ((c+lane)&15)*4]  (canonical b128)
    if (w == 2) {
#pragma unroll
        for (int cc = 0; cc < 16; ++cc) {
            const int i = cc >> 1, j = (cc & 1) * 4;
            *(float4*)&sm[BUFA_OFF + lane * 64 + (((cc + lane) & 15) << 2)] =
                make_float4(acc[i][j], acc[i][j + 1], acc[i][j + 2], acc[i][j + 3]);
        }
    }
    if (w == 3) {
#pragma unroll
        for (int cc = 0; cc < 16; ++cc) {
            const int i = cc >> 1, j = (cc & 1) * 4;
            *(float4*)&sm[BUFB_OFF + lane * 64 + (((cc + lane) & 15) << 2)] =
                make_float4(acc[i][j], acc[i][j + 1], acc[i][j + 2], acc[i][j + 3]);
        }
    }
    __syncthreads();                                           // B2
    if (w == 0) {
#pragma unroll
        for (int cc = 0; cc < 16; ++cc) {
            const int i = cc >> 1, j = (cc & 1) * 4;
            float4 u = *(float4*)&sm[BUFA_OFF + lane * 64 + (((cc + lane) & 15) << 2)];
            acc[i][j] += u.x; acc[i][j+1] += u.y; acc[i][j+2] += u.z; acc[i][j+3] += u.w;
        }
    }
    if (w == 1) {
#pragma unroll
        for (int cc = 0; cc < 16; ++cc) {
            const int i = cc >> 1, j = (cc & 1) * 4;
            float4 u = *(float4*)&sm[BUFB_OFF + lane * 64 + (((cc + lane) & 15) << 2)];
            acc[i][j] += u.x; acc[i][j+1] += u.y; acc[i][j+2] += u.z; acc[i][j+3] += u.w;
        }
    }
    __syncthreads();                                           // B3
    if (w == 1) {
#pragma unroll
        for (int cc = 0; cc < 16; ++cc) {
            const int i = cc >> 1, j = (cc & 1) * 4;
            *(float4*)&sm[BUFA_OFF + lane * 64 + (((cc + lane) & 15) << 2)] =
                make_float4(acc[i][j], acc[i][j + 1], acc[i][j + 2], acc[i][j + 3]);
        }
    }
    __syncthreads();                                           // B4
    if (w == 0) {
        float* pb = part + ((size_t)nh * CH + chunk) * PART_STRIDE;
#pragma unroll
        for (int cc = 0; cc < 16; ++cc) {
            const int i = cc >> 1, j = (cc & 1) * 4;
            float4 u = *(float4*)&sm[BUFA_OFF + lane * 64 + (((cc + lane) & 15) << 2)];
            // coalesced: fixed cc -> lanes cover 1 KB contiguous
            *(float4*)(pb + (cc << 8) + (lane << 2)) =
                make_float4(acc[i][j] + u.x, acc[i][j + 1] + u.y,
                            acc[i][j + 2] + u.z, acc[i][j + 3] + u.w);
        }
        pb[KVSZ + lane] = ksumF;    // Ksum[d=lane]
    }
}

// ---------------------------------------------------------------------------
// k2: sum CH partials -> fin[nh][4160] (layout-agnostic elementwise sum)
// ---------------------------------------------------------------------------
__global__ __launch_bounds__(256) void k2_reduce(const float* __restrict__ part,
                                                 float* __restrict__ fin) {
    const int idx = blockIdx.x * 256 + threadIdx.x;
    if (idx >= NHTOT * PART_STRIDE) return;
    const int nh = idx / PART_STRIDE;
    const int j  = idx - nh * PART_STRIDE;
    const float* p = part + (size_t)nh * CH * PART_STRIDE + j;
    float s = 0.f;
#pragma unroll
    for (int cx = 0; cx < CH; ++cx) s += p[(size_t)cx * PART_STRIDE];
    fin[idx] = s;
}

// ---------------------------------------------------------------------------
// k3: out = (Qf·KV) / (Qf·Ksum + eps). 128 thr (2 waves), LT=128 l-rows,
// 8x8 per-thread tile, Q staged bf16. De-swizzles fin's lane-major layout
// into KVs[d][e] during load (scalar LDS writes; coalesced global reads).
// ---------------------------------------------------------------------------
#define LT3  128
#define QSTR 72   // ushort row stride: bf16 q reads broadcast/conflict-free
__global__ __launch_bounds__(128, 2) void k3_out(const float* __restrict__ Qin,
                                                 const float* __restrict__ fin,
                                                 float* __restrict__ out) {
    __shared__ unsigned short Qs[LT3 * QSTR];   // 18 KB
    __shared__ float KVs[DD * DD];              // 16 KB
    __shared__ float Ksm[DD];
    const int blk = blockIdx.x;
    const int nh  = blk >> 5;
    const int lc  = blk & 31;
    const int n = nh >> 3, h = nh & 7;
    const int t = threadIdx.x;
    const int w = t >> 6, lane = t & 63;

    // load final KV (de-swizzle: f = c*256 + l*4 + m -> d,e) + Ksum
    const float* fb = fin + (size_t)nh * PART_STRIDE;
    for (int base = t * 4; base < KVSZ; base += 512) {
        float4 v = *(const float4*)(fb + base);
        const int cc = base >> 8;
        const int l  = (base & 255) >> 2;
        const float vals[4] = {v.x, v.y, v.z, v.w};
#pragma unroll
        for (int m = 0; m < 4; ++m) {
            const int k = (cc << 2) + m;
            const int d = ((l & 7) << 3) + (k >> 3);
            const int e = ((l >> 3) << 3) + (k & 7);
            KVs[d * DD + e] = vals[m];
        }
    }
    if (t < DD) Ksm[t] = fb[KVSZ + t];

    // stage Q (feature-mapped, bf16)
    const int r = t >> 4, c = (t & 15) * 4;
    const float* Qb = Qin + ((size_t)n * LQ + (size_t)lc * LT3) * ROWSTRIDE
                      + (size_t)h * DD + c;
    for (int rr = r; rr < LT3; rr += 8) {
        float4 q = *(const float4*)(Qb + (size_t)rr * ROWSTRIDE);
        float4 qf = fmap4(q);
        unsigned int w0 = (unsigned int)f2bf(qf.x) | ((unsigned int)f2bf(qf.y) << 16);
        unsigned int w1 = (unsigned int)f2bf(qf.z) | ((unsigned int)f2bf(qf.w) << 16);
        *(uint2*)&Qs[rr * QSTR + c] = make_uint2(w0, w1);
    }
    __syncthreads();

    const int e0 = (lane >> 3) * 8;
    const int rbase = w * 64 + (lane & 7);     // rows rbase + 8i
    float acc[8][8] = {};
    float z[8] = {};

#pragma unroll
    for (int dch = 0; dch < DD; dch += 4) {
        float4 km4 = *(const float4*)&Ksm[dch];
        float kmv[4] = {km4.x, km4.y, km4.z, km4.w};
        float qf[8][4];
#pragma unroll
        for (int i = 0; i < 8; ++i) {
            uint2 qw = *(const uint2*)&Qs[(rbase + 8 * i) * QSTR + dch];
            qf[i][0] = __uint_as_float(qw.x << 16);
            qf[i][1] = __uint_as_float(qw.x & 0xffff0000u);
            qf[i][2] = __uint_as_float(qw.y << 16);
            qf[i][3] = __uint_as_float(qw.y & 0xffff0000u);
        }
        float kv[4][8];
#pragma unroll
        for (int dd = 0; dd < 4; ++dd) {
            float4 a = *(const float4*)&KVs[(dch + dd) * DD + e0];
            float4 b = *(const float4*)&KVs[(dch + dd) * DD + e0 + 4];
            kv[dd][0] = a.x; kv[dd][1] = a.y; kv[dd][2] = a.z; kv[dd][3] = a.w;
            kv[dd][4] = b.x; kv[dd][5] = b.y; kv[dd][6] = b.z; kv[dd][7] = b.w;
        }
#pragma unroll
        for (int i = 0; i < 8; ++i)
#pragma unroll
            for (int dd = 0; dd < 4; ++dd) {
                z[i] += qf[i][dd] * kmv[dd];
#pragma unroll
                for (int j = 0; j < 8; ++j)
                    acc[i][j] += qf[i][dd] * kv[dd][j];
            }
    }

    float* ob = out + ((size_t)n * LQ + (size_t)lc * LT3) * ROWSTRIDE
                + (size_t)h * DD;
#pragma unroll
    for (int i = 0; i < 8; ++i) {
        float zi = 1.f / (z[i] + EPSF);
        const size_t row = (size_t)(rbase + 8 * i) * ROWSTRIDE;
        *(float4*)(ob + row + e0) =
            make_float4(acc[i][0] * zi, acc[i][1] * zi, acc[i][2] * zi, acc[i][3] * zi);
        *(float4*)(ob + row + e0 + 4) =
            make_float4(acc[i][4] * zi, acc[i][5] * zi, acc[i][6] * zi, acc[i][7] * zi);
    }
}

// ---------------------------------------------------------------------------
extern "C" void kernel_launch(void* const* d_in, const int* in_sizes, int n_in,
                              void* d_out, int out_size, void* d_ws, size_t ws_size,
                              hipStream_t stream) {
    const float* Q = (const float*)d_in[0];
    const float* K = (const float*)d_in[1];
    const float* V = (const float*)d_in[2];
    float* out = (float*)d_out;

    float* ws   = (float*)d_ws;
    float* part = ws;                                        // 32*32*4160 floats (~17 MB)
    float* fin  = ws + (size_t)NHTOT * CH * PART_STRIDE;     // 32*4160 floats

    k1_kv<<<NHTOT * CH, 256, 0, stream>>>(K, V, part);
    k2_reduce<<<(NHTOT * PART_STRIDE + 255) / 256, 256, 0, stream>>>(part, fin);
    k3_out<<<NHTOT * (LQ / LT3), 128, 0, stream>>>(Q, fin, out);
}